// Round 1
// baseline (465.720 us; speedup 1.0000x reference)
//
#include <hip/hip_runtime.h>
#include <hip/hip_bf16.h>
#include <math.h>

#define NB   1024
#define NS   60
#define ND   256
#define NH   1024
#define NE   8
#define NCAP 256
#define NTOK (NCAP*NS)      // 15360 tokens per expert
#define BM   64
#define NBLK (NTOK/BM)      // 240 row-tiles per expert
#define A_PAD 264           // 256 + 8 bf16 pad -> 2-way LDS conflict (free)
#define P_PAD 136           // 128 + 8 bf16 pad

typedef __attribute__((ext_vector_type(8))) short  short8;
typedef __attribute__((ext_vector_type(4))) float  floatx4;

__device__ __forceinline__ unsigned short f2bf(float f) {
    union { float f; unsigned u; } cv; cv.f = f;
    unsigned u = cv.u;
    u += 0x7FFFu + ((u >> 16) & 1u);   // round-to-nearest-even
    return (unsigned short)(u >> 16);
}

// ---------------- prep: x -> bf16 copy (xb) + fp32 residual accumulator (acc = x)
__global__ void k_prep_x(const float* __restrict__ x, unsigned short* __restrict__ xb,
                         float* __restrict__ acc, int n4) {
    int i = blockIdx.x * blockDim.x + threadIdx.x;
    if (i >= n4) return;
    float4 v = ((const float4*)x)[i];
    ((float4*)acc)[i] = v;
    ushort4 o;
    o.x = f2bf(v.x); o.y = f2bf(v.y); o.z = f2bf(v.z); o.w = f2bf(v.w);
    ((ushort4*)xb)[i] = o;
}

// ---------------- pack W1 [E,256,1024] fp32 -> MFMA B-fragment order bf16
// fragment id f = (e*64 + hnt)*8 + kt ; elem = f*512 + lane*8 + j
// represents W1[e][kt*32 + (lane>>4)*8 + j][hnt*16 + (lane&15)]
__global__ void k_pack_w1(const float* __restrict__ W1, unsigned short* __restrict__ W1b) {
    int tid = blockIdx.x * blockDim.x + threadIdx.x;   // 262144
    int lane = tid & 63;
    int f = tid >> 6;
    int kt  = f & 7;
    int hnt = (f >> 3) & 63;
    int e   = f >> 9;
    int n = hnt * 16 + (lane & 15);
    int k = kt * 32 + (lane >> 4) * 8;
    const float* src = W1 + ((size_t)(e * 256 + k)) * 1024 + n;
    ushort4 a, b;
    a.x = f2bf(src[0 * 1024]); a.y = f2bf(src[1 * 1024]);
    a.z = f2bf(src[2 * 1024]); a.w = f2bf(src[3 * 1024]);
    b.x = f2bf(src[4 * 1024]); b.y = f2bf(src[5 * 1024]);
    b.z = f2bf(src[6 * 1024]); b.w = f2bf(src[7 * 1024]);
    ((ushort4*)W1b)[tid * 2]     = a;
    ((ushort4*)W1b)[tid * 2 + 1] = b;
}

// ---------------- pack W2 [E,1024,256] fp32 -> fragment order bf16
// fragment id f = (e*16 + dnt)*32 + kt ; represents
// W2[e][kt*32 + (lane>>4)*8 + j][dnt*16 + (lane&15)]
__global__ void k_pack_w2(const float* __restrict__ W2, unsigned short* __restrict__ W2b) {
    int tid = blockIdx.x * blockDim.x + threadIdx.x;   // 262144
    int lane = tid & 63;
    int f = tid >> 6;
    int kt  = f & 31;
    int dnt = (f >> 5) & 15;
    int e   = f >> 9;
    int n = dnt * 16 + (lane & 15);
    int k = kt * 32 + (lane >> 4) * 8;
    const float* src = W2 + ((size_t)(e * 1024 + k)) * 256 + n;
    ushort4 a, b;
    a.x = f2bf(src[0 * 256]); a.y = f2bf(src[1 * 256]);
    a.z = f2bf(src[2 * 256]); a.w = f2bf(src[3 * 256]);
    b.x = f2bf(src[4 * 256]); b.y = f2bf(src[5 * 256]);
    b.z = f2bf(src[6 * 256]); b.w = f2bf(src[7 * 256]);
    ((ushort4*)W2b)[tid * 2]     = a;
    ((ushort4*)W2b)[tid * 2 + 1] = b;
}

// ---------------- routing: logits = x_flat @ W_switch + b ; softmax -> probs [B,8]
// fp32 throughout (selection fidelity). One block per batch element.
__global__ void k_route(const float* __restrict__ x, const float* __restrict__ Wsw,
                        const float* __restrict__ bsw, float* __restrict__ probs) {
    int b = blockIdx.x;
    int tid = threadIdx.x;
    const float* xr = x + (size_t)b * (NS * ND);
    float a[8];
#pragma unroll
    for (int e = 0; e < 8; ++e) a[e] = 0.f;
    for (int it = 0; it < 60; ++it) {
        int j = tid + it * 256;
        float v = xr[j];
        const float4* w = (const float4*)(Wsw + (size_t)j * 8);
        float4 w0 = w[0], w1 = w[1];
        a[0] += v * w0.x; a[1] += v * w0.y; a[2] += v * w0.z; a[3] += v * w0.w;
        a[4] += v * w1.x; a[5] += v * w1.y; a[6] += v * w1.z; a[7] += v * w1.w;
    }
#pragma unroll
    for (int off = 32; off >= 1; off >>= 1) {
#pragma unroll
        for (int e = 0; e < 8; ++e) a[e] += __shfl_xor(a[e], off);
    }
    __shared__ float red[32];
    __shared__ float ll[8];
    int lane = tid & 63, wv = tid >> 6;
    if (lane == 0) {
#pragma unroll
        for (int e = 0; e < 8; ++e) red[wv * 8 + e] = a[e];
    }
    __syncthreads();
    if (tid < 8) {
        float l = red[0 * 8 + tid] + red[1 * 8 + tid] + red[2 * 8 + tid] + red[3 * 8 + tid]
                + bsw[tid];
        ll[tid] = l;
    }
    __syncthreads();
    if (tid < 8) {
        float m = ll[0];
#pragma unroll
        for (int j = 1; j < 8; ++j) m = fmaxf(m, ll[j]);
        float s = 0.f;
#pragma unroll
        for (int j = 0; j < 8; ++j) s += expf(ll[j] - m);
        probs[b * 8 + tid] = expf(ll[tid] - m) / s;
    }
}

// ---------------- top-CAP per expert by rank (matches lax.top_k tie-by-lower-index)
__global__ __launch_bounds__(1024)
void k_topk(const float* __restrict__ probs, int* __restrict__ idxb) {
    __shared__ float v[NB];
    int e = blockIdx.x;
    int tid = threadIdx.x;
    v[tid] = probs[tid * 8 + e];
    __syncthreads();
    float mv = v[tid];
    int cnt = 0;
    for (int j = 0; j < NB; ++j) {
        float vj = v[j];
        cnt += (vj > mv) || (vj == mv && j < tid);
    }
    if (cnt < NCAP) idxb[e * NCAP + cnt] = tid;
}

// ---------------- fused expert MLP: gather -> GEMM1 -> GELU -> GEMM2 -> atomic scatter
__global__ __launch_bounds__(256, 2)
void k_mlp(const unsigned short* __restrict__ xb,
           const unsigned short* __restrict__ W1b,
           const unsigned short* __restrict__ W2b,
           const float* __restrict__ b1,
           const float* __restrict__ b2,
           const int* __restrict__ idxb,
           float* __restrict__ acc) {
    __shared__ unsigned short Alds[BM * A_PAD];   // 33792 B
    __shared__ unsigned short Plds[BM * P_PAD];   // 17408 B

    int e  = blockIdx.x / NBLK;
    int bm = blockIdx.x % NBLK;
    int tb = bm * BM;
    int tid = threadIdx.x;
    int lane = tid & 63, wv = tid >> 6;
    int quad = lane >> 4, l15 = lane & 15;

    // stage A tile [64 x 256] bf16 (gathered token rows)
    {
        int lr = tid >> 2;
        int s4 = tid & 3;
        int t = tb + lr;
        int c = t / 60;
        int s = t - c * 60;
        int bidx = idxb[e * NCAP + c];
        const unsigned short* src = xb + ((size_t)(bidx * 60 + s)) * 256;
#pragma unroll
        for (int j = 0; j < 8; ++j) {
            int seg = j * 4 + s4;
            *(short8*)(&Alds[lr * A_PAD + seg * 8]) = *(const short8*)(src + seg * 8);
        }
    }
    __syncthreads();

    floatx4 acc2[4][4];
#pragma unroll
    for (int mt = 0; mt < 4; ++mt)
#pragma unroll
        for (int nt = 0; nt < 4; ++nt) acc2[mt][nt] = 0.f;

    for (int ch = 0; ch < 8; ++ch) {
        // ---- GEMM1: P[64,128-chunk] ; wave owns cols [wv*32, wv*32+32)
        floatx4 pacc[4][2];
#pragma unroll
        for (int mt = 0; mt < 4; ++mt) { pacc[mt][0] = 0.f; pacc[mt][1] = 0.f; }
#pragma unroll
        for (int kt = 0; kt < 8; ++kt) {
            short8 af[4];
#pragma unroll
            for (int mt = 0; mt < 4; ++mt)
                af[mt] = *(const short8*)(&Alds[(mt * 16 + l15) * A_PAD + kt * 32 + quad * 8]);
#pragma unroll
            for (int nt = 0; nt < 2; ++nt) {
                int hnt = ch * 8 + wv * 2 + nt;
                short8 bf = *(const short8*)(W1b + ((size_t)((e * 64 + hnt) * 8 + kt)) * 512 + lane * 8);
#pragma unroll
                for (int mt = 0; mt < 4; ++mt)
                    pacc[mt][nt] = __builtin_amdgcn_mfma_f32_16x16x32_bf16(af[mt], bf, pacc[mt][nt], 0, 0, 0);
            }
        }
        // wait for previous chunk's GEMM2 reads before overwriting Plds
        __syncthreads();
        // ---- bias + exact GELU -> Plds (bf16, A-operand staging)
#pragma unroll
        for (int nt = 0; nt < 2; ++nt) {
            int cl = wv * 32 + nt * 16 + l15;          // col within chunk [0,128)
            float bias = b1[e * NH + ch * 128 + cl];
#pragma unroll
            for (int mt = 0; mt < 4; ++mt) {
#pragma unroll
                for (int r = 0; r < 4; ++r) {
                    float vv = pacc[mt][nt][r] + bias;
                    float g = 0.5f * vv * (1.0f + erff(vv * 0.70710678118654752f));
                    Plds[(mt * 16 + quad * 4 + r) * P_PAD + cl] = f2bf(g);
                }
            }
        }
        __syncthreads();
        // ---- GEMM2: acc2 += P_chunk @ W2[chunk rows] ; wave owns cols [wv*64, wv*64+64)
#pragma unroll
        for (int kt = 0; kt < 4; ++kt) {
            short8 pf[4];
#pragma unroll
            for (int mt = 0; mt < 4; ++mt)
                pf[mt] = *(const short8*)(&Plds[(mt * 16 + l15) * P_PAD + kt * 32 + quad * 8]);
            int kg = ch * 4 + kt;
#pragma unroll
            for (int nt = 0; nt < 4; ++nt) {
                int dnt = wv * 4 + nt;
                short8 wf = *(const short8*)(W2b + ((size_t)((e * 16 + dnt) * 32 + kg)) * 512 + lane * 8);
#pragma unroll
                for (int mt = 0; mt < 4; ++mt)
                    acc2[mt][nt] = __builtin_amdgcn_mfma_f32_16x16x32_bf16(pf[mt], wf, acc2[mt][nt], 0, 0, 0);
            }
        }
    }

    // ---- epilogue: + b2, atomic scatter-add into acc[b,s,:]
    float b2v[4];
#pragma unroll
    for (int nt = 0; nt < 4; ++nt) b2v[nt] = b2[e * ND + wv * 64 + nt * 16 + l15];
#pragma unroll
    for (int mt = 0; mt < 4; ++mt) {
#pragma unroll
        for (int r = 0; r < 4; ++r) {
            int t = tb + mt * 16 + quad * 4 + r;
            int c = t / 60;
            int s = t - c * 60;
            int bidx = idxb[e * NCAP + c];
            float* dst = acc + ((size_t)(bidx * 60 + s)) * 256 + wv * 64 + l15;
#pragma unroll
            for (int nt = 0; nt < 4; ++nt) {
                unsafeAtomicAdd(dst + nt * 16, acc2[mt][nt][r] + b2v[nt]);
            }
        }
    }
}

// ---------------- residual already folded in acc; LayerNorm -> out (fp32)
__global__ void k_ln(const float* __restrict__ acc, const float* __restrict__ gamma,
                     const float* __restrict__ beta, float* __restrict__ out) {
    int row = blockIdx.x * 4 + (threadIdx.x >> 6);
    int lane = threadIdx.x & 63;
    float4 v = ((const float4*)(acc + (size_t)row * 256))[lane];
    float s = v.x + v.y + v.z + v.w;
    float q = v.x * v.x + v.y * v.y + v.z * v.z + v.w * v.w;
#pragma unroll
    for (int off = 32; off >= 1; off >>= 1) {
        s += __shfl_xor(s, off);
        q += __shfl_xor(q, off);
    }
    float mu  = s * (1.0f / 256.0f);
    float var = q * (1.0f / 256.0f) - mu * mu;
    float rs  = rsqrtf(var + 1e-5f);
    float4 g  = ((const float4*)gamma)[lane];
    float4 bt = ((const float4*)beta)[lane];
    float4 o;
    o.x = (v.x - mu) * rs * g.x + bt.x;
    o.y = (v.y - mu) * rs * g.y + bt.y;
    o.z = (v.z - mu) * rs * g.z + bt.z;
    o.w = (v.w - mu) * rs * g.w + bt.w;
    ((float4*)(out + (size_t)row * 256))[lane] = o;
}

extern "C" void kernel_launch(void* const* d_in, const int* in_sizes, int n_in,
                              void* d_out, int out_size, void* d_ws, size_t ws_size,
                              hipStream_t stream) {
    const float* x     = (const float*)d_in[0];
    const float* Wsw   = (const float*)d_in[1];
    const float* bsw   = (const float*)d_in[2];
    const float* W1    = (const float*)d_in[3];
    const float* b1    = (const float*)d_in[4];
    const float* W2    = (const float*)d_in[5];
    const float* b2    = (const float*)d_in[6];
    const float* gamma = (const float*)d_in[7];
    const float* beta  = (const float*)d_in[8];
    float* out = (float*)d_out;

    char* ws = (char*)d_ws;
    size_t off = 0;
    auto alloc = [&](size_t bytes) { void* p = ws + off; off += (bytes + 255) & ~255ull; return p; };
    float*          probs = (float*)alloc((size_t)NB * NE * 4);
    int*            idxb  = (int*)alloc((size_t)NE * NCAP * 4);
    unsigned short* xb    = (unsigned short*)alloc((size_t)NB * NS * ND * 2);
    unsigned short* W1b   = (unsigned short*)alloc((size_t)NE * ND * NH * 2);
    unsigned short* W2b   = (unsigned short*)alloc((size_t)NE * NH * ND * 2);
    float*          acc   = (float*)alloc((size_t)NB * NS * ND * 4);
    (void)ws_size; (void)in_sizes; (void)n_in; (void)out_size;

    int n4 = NB * NS * ND / 4;
    k_prep_x<<<(n4 + 255) / 256, 256, 0, stream>>>(x, xb, acc, n4);
    k_pack_w1<<<1024, 256, 0, stream>>>(W1, W1b);
    k_pack_w2<<<1024, 256, 0, stream>>>(W2, W2b);
    k_route<<<NB, 256, 0, stream>>>(x, Wsw, bsw, probs);
    k_topk<<<NE, 1024, 0, stream>>>(probs, idxb);
    k_mlp<<<NE * NBLK, 256, 0, stream>>>(xb, W1b, W2b, b1, b2, idxb, acc);
    k_ln<<<NB * NS / 4, 256, 0, stream>>>(acc, gamma, beta, out);
}